// Round 5
// baseline (146.742 us; speedup 1.0000x reference)
//
#include <hip/hip_runtime.h>

#define N_NODES 100000
#define N_EDGES 3200000
#define NB 782              // buckets of 128 nodes: ceil(100000/128)
#define NHB 256             // histogram / binning blocks
#define EPB (N_EDGES / NHB) // 12500 edges per binning block (exact)
#define BS 256

typedef int iv4 __attribute__((ext_vector_type(4)));

__device__ __forceinline__ iv4 nt_load4(const int* p) {
    return __builtin_nontemporal_load((const iv4*)p);
}

// ---------- phase 1: per-(bucket,block) histogram ----------
__global__ void k_hist(const int* __restrict__ dst, int* __restrict__ histM) {
    __shared__ int h[NB];
    int tid = threadIdx.x, blk = blockIdx.x;
    for (int b = tid; b < NB; b += BS) h[b] = 0;
    __syncthreads();
    int base = blk * EPB;
    for (int i = base + tid * 4; i < base + EPB; i += BS * 4) {
        iv4 d = nt_load4(dst + i);
        atomicAdd(&h[d.x >> 7], 1);
        atomicAdd(&h[d.y >> 7], 1);
        atomicAdd(&h[d.z >> 7], 1);
        atomicAdd(&h[d.w >> 7], 1);
    }
    __syncthreads();
    for (int b = tid; b < NB; b += BS) histM[b * NHB + blk] = h[b];
}

// ---------- phase 2a: exclusive scan along blocks, per bucket ----------
__global__ void k_scan(int* __restrict__ histM, int* __restrict__ btot) {
    __shared__ int sh[BS];
    int b = blockIdx.x, tid = threadIdx.x;
    int c = histM[b * NHB + tid];
    sh[tid] = c;
    __syncthreads();
    for (int off = 1; off < BS; off <<= 1) {
        int t = (tid >= off) ? sh[tid - off] : 0;
        __syncthreads();
        sh[tid] += t;
        __syncthreads();
    }
    histM[b * NHB + tid] = sh[tid] - c;  // exclusive within bucket
    if (tid == BS - 1) btot[b] = sh[tid];
}

// ---------- phase 2b: exclusive scan of bucket totals ----------
__global__ void k_base(const int* __restrict__ btot, int* __restrict__ bbase) {
    __shared__ int sh[BS];
    int tid = threadIdx.x;
    int v[4];
    int s = 0;
#pragma unroll
    for (int j = 0; j < 4; ++j) {
        int idx = tid * 4 + j;
        v[j] = (idx < NB) ? btot[idx] : 0;
        s += v[j];
    }
    sh[tid] = s;
    __syncthreads();
    for (int off = 1; off < BS; off <<= 1) {
        int t = (tid >= off) ? sh[tid - off] : 0;
        __syncthreads();
        sh[tid] += t;
        __syncthreads();
    }
    int base = sh[tid] - s;
#pragma unroll
    for (int j = 0; j < 4; ++j) {
        int idx = tid * 4 + j;
        if (idx < NB) bbase[idx] = base;
        base += v[j];
    }
}

// ---------- phase 3: scatter edges into bucket segments ----------
// packed = (src << 7) | (dst & 127); src < 2^17, fits 24 bits.
__global__ void k_bin(const int* __restrict__ src, const int* __restrict__ dst,
                      const int* __restrict__ histM, const int* __restrict__ bbase,
                      unsigned* __restrict__ binned) {
    __shared__ int off[NB];
    int tid = threadIdx.x, blk = blockIdx.x;
    for (int b = tid; b < NB; b += BS)
        off[b] = bbase[b] + histM[b * NHB + blk];
    __syncthreads();
    int base = blk * EPB;
    for (int i = base + tid * 4; i < base + EPB; i += BS * 4) {
        iv4 s4 = nt_load4(src + i);
        iv4 d4 = nt_load4(dst + i);
        int p0 = atomicAdd(&off[d4.x >> 7], 1);
        binned[p0] = ((unsigned)s4.x << 7) | (unsigned)(d4.x & 127);
        int p1 = atomicAdd(&off[d4.y >> 7], 1);
        binned[p1] = ((unsigned)s4.y << 7) | (unsigned)(d4.y & 127);
        int p2 = atomicAdd(&off[d4.z >> 7], 1);
        binned[p2] = ((unsigned)s4.z << 7) | (unsigned)(d4.z & 127);
        int p3 = atomicAdd(&off[d4.w >> 7], 1);
        binned[p3] = ((unsigned)s4.w << 7) | (unsigned)(d4.w & 127);
    }
}

// ---------- phase 4: per-bucket degree + node1 (dinv, s) ----------
__global__ void k_deg_node1(const unsigned* __restrict__ binned,
                            const int* __restrict__ bbase, const int* __restrict__ btot,
                            const float* __restrict__ x,
                            float* __restrict__ dinv, float* __restrict__ s) {
    __shared__ int cnt[4][136];
    int tid = threadIdx.x, b = blockIdx.x;
    for (int i = tid; i < 4 * 136; i += BS) ((int*)cnt)[i] = 0;
    __syncthreads();
    int st = bbase[b], en = st + btot[b];
    int rep = tid & 3;
    for (int i = st + tid; i < en; i += BS) {
        unsigned rd = __builtin_nontemporal_load(binned + i);
        atomicAdd(&cnt[rep][rd & 127], 1);
    }
    __syncthreads();
    int node = b * 128 + tid;
    if (tid < 128 && node < N_NODES) {
        int d = cnt[0][tid] + cnt[1][tid] + cnt[2][tid] + cnt[3][tid];
        float di = rsqrtf((float)(d + 1));  // +1 self-loop
        dinv[node] = di;
        s[node] = di * x[node];
    }
}

// ---------- phase 5: per-bucket scatter1 + layer-1 MLP -> z ----------
__global__ void k_s1n2(const unsigned* __restrict__ binned,
                       const int* __restrict__ bbase, const int* __restrict__ btot,
                       const float* __restrict__ dinv, const float* __restrict__ s,
                       const float* __restrict__ W1, const float* __restrict__ b1,
                       const float* __restrict__ W2, float2* __restrict__ z) {
    __shared__ float acc[4][136];
    int tid = threadIdx.x, b = blockIdx.x;
    for (int i = tid; i < 4 * 136; i += BS) ((float*)acc)[i] = 0.f;
    __syncthreads();
    int st = bbase[b], en = st + btot[b];
    int rep = tid & 3;
    for (int i = st + tid; i < en; i += BS) {
        unsigned rd = __builtin_nontemporal_load(binned + i);
        atomicAdd(&acc[rep][rd & 127], s[rd >> 7]);
    }
    __syncthreads();
    int node = b * 128 + tid;
    if (tid < 128 && node < N_NODES) {
        float aggv = acc[0][tid] + acc[1][tid] + acc[2][tid] + acc[3][tid];
        float di = dinv[node];
        float a = di * (aggv + s[node]);  // s[node] = self-loop term
        float z0 = 0.f, z1 = 0.f;
#pragma unroll
        for (int f = 0; f < 16; ++f) {
            float h = fmaxf(a * W1[f] + b1[f], 0.f);
            z0 += h * W2[2 * f + 0];
            z1 += h * W2[2 * f + 1];
        }
        z[node] = make_float2(di * z0, di * z1);
    }
}

// ---------- phase 6: per-bucket scatter2 + epilogue -> out ----------
__global__ void k_s2out(const unsigned* __restrict__ binned,
                        const int* __restrict__ bbase, const int* __restrict__ btot,
                        const float* __restrict__ dinv, const float2* __restrict__ z,
                        const float* __restrict__ b2, float2* __restrict__ out) {
    __shared__ float accx[4][136], accy[4][136];
    int tid = threadIdx.x, b = blockIdx.x;
    for (int i = tid; i < 4 * 136; i += BS) {
        ((float*)accx)[i] = 0.f;
        ((float*)accy)[i] = 0.f;
    }
    __syncthreads();
    int st = bbase[b], en = st + btot[b];
    int rep = tid & 3;
    for (int i = st + tid; i < en; i += BS) {
        unsigned rd = __builtin_nontemporal_load(binned + i);
        float2 zz = z[rd >> 7];
        atomicAdd(&accx[rep][rd & 127], zz.x);
        atomicAdd(&accy[rep][rd & 127], zz.y);
    }
    __syncthreads();
    int node = b * 128 + tid;
    if (tid < 128 && node < N_NODES) {
        float ax = accx[0][tid] + accx[1][tid] + accx[2][tid] + accx[3][tid];
        float ay = accy[0][tid] + accy[1][tid] + accy[2][tid] + accy[3][tid];
        float di = dinv[node];
        float2 zz = z[node];
        out[node] = make_float2(di * (ax + zz.x) + b2[0],
                                di * (ay + zz.y) + b2[1]);
    }
}

// ---------- fallback (device atomics), used only if ws too small ----------
__global__ void f_deg(const int* __restrict__ dst, int* __restrict__ deg) {
    int i = blockIdx.x * blockDim.x + threadIdx.x;
    if (i < N_EDGES) atomicAdd(&deg[dst[i]], 1);
}
__global__ void f_node1(const float* __restrict__ x, const int* __restrict__ deg,
                        float* __restrict__ dinv, float* __restrict__ s) {
    int v = blockIdx.x * blockDim.x + threadIdx.x;
    if (v < N_NODES) {
        float di = rsqrtf((float)(deg[v] + 1));
        dinv[v] = di;
        s[v] = di * x[v];
    }
}
__global__ void f_scatter1(const int* __restrict__ src, const int* __restrict__ dst,
                           const float* __restrict__ s, float* __restrict__ agg1) {
    int i = blockIdx.x * blockDim.x + threadIdx.x;
    if (i < N_EDGES) atomicAdd(&agg1[dst[i]], s[src[i]]);
}
__global__ void f_node2(const float* __restrict__ dinv, const float* __restrict__ s,
                        const float* __restrict__ agg1, const float* __restrict__ W1,
                        const float* __restrict__ b1, const float* __restrict__ W2,
                        float2* __restrict__ z) {
    int v = blockIdx.x * blockDim.x + threadIdx.x;
    if (v < N_NODES) {
        float di = dinv[v];
        float a = di * (agg1[v] + s[v]);
        float z0 = 0.f, z1 = 0.f;
#pragma unroll
        for (int f = 0; f < 16; ++f) {
            float h = fmaxf(a * W1[f] + b1[f], 0.f);
            z0 += h * W2[2 * f + 0];
            z1 += h * W2[2 * f + 1];
        }
        z[v] = make_float2(di * z0, di * z1);
    }
}
__global__ void f_scatter2(const int* __restrict__ src, const int* __restrict__ dst,
                           const float2* __restrict__ z, float* __restrict__ agg2) {
    int i = blockIdx.x * blockDim.x + threadIdx.x;
    if (i < N_EDGES) {
        float2 zz = z[src[i]];
        int d = dst[i];
        atomicAdd(&agg2[2 * d + 0], zz.x);
        atomicAdd(&agg2[2 * d + 1], zz.y);
    }
}
__global__ void f_out(const float* __restrict__ dinv, const float2* __restrict__ z,
                      const float2* __restrict__ agg2, const float* __restrict__ b2,
                      float2* __restrict__ out) {
    int v = blockIdx.x * blockDim.x + threadIdx.x;
    if (v < N_NODES) {
        float di = dinv[v];
        float2 a = agg2[v], zz = z[v];
        out[v] = make_float2(di * (a.x + zz.x) + b2[0], di * (a.y + zz.y) + b2[1]);
    }
}

// ---------- launch ----------
extern "C" void kernel_launch(void* const* d_in, const int* in_sizes, int n_in,
                              void* d_out, int out_size, void* d_ws, size_t ws_size,
                              hipStream_t stream) {
    const float* x  = (const float*)d_in[0];
    const int* eidx = (const int*)d_in[1];
    const float* W1 = (const float*)d_in[2];
    const float* b1 = (const float*)d_in[3];
    const float* W2 = (const float*)d_in[4];
    const float* b2 = (const float*)d_in[5];
    float* out = (float*)d_out;

    const int n = N_NODES;
    const int* src = eidx;
    const int* dst = eidx + N_EDGES;

    // workspace layout (32-bit words):
    // histM[NB*NHB] | btot[1024] | bbase[1024] | binned[E] | dinv[n] | s[n] | z[2n]
    size_t oHist = 0;
    size_t oBtot = oHist + (size_t)NB * NHB;
    size_t oBbase = oBtot + 1024;
    size_t oBin  = oBbase + 1024;
    size_t oDinv = oBin + N_EDGES;
    size_t oS    = oDinv + n;
    size_t oZ    = oS + n;
    size_t need  = (oZ + 2 * n) * sizeof(int);

    if (ws_size >= need) {
        int* wsI = (int*)d_ws;
        int* histM = wsI + oHist;
        int* btot  = wsI + oBtot;
        int* bbase = wsI + oBbase;
        unsigned* binned = (unsigned*)(wsI + oBin);
        float* dinv = (float*)(wsI + oDinv);
        float* s    = (float*)(wsI + oS);
        float* z    = (float*)(wsI + oZ);

        k_hist<<<NHB, BS, 0, stream>>>(dst, histM);
        k_scan<<<NB, BS, 0, stream>>>(histM, btot);
        k_base<<<1, BS, 0, stream>>>(btot, bbase);
        k_bin<<<NHB, BS, 0, stream>>>(src, dst, histM, bbase, binned);
        k_deg_node1<<<NB, BS, 0, stream>>>(binned, bbase, btot, x, dinv, s);
        k_s1n2<<<NB, BS, 0, stream>>>(binned, bbase, btot, dinv, s, W1, b1, W2,
                                      (float2*)z);
        k_s2out<<<NB, BS, 0, stream>>>(binned, bbase, btot, dinv, (const float2*)z,
                                       b2, (float2*)out);
    } else {
        float* ws = (float*)d_ws;
        int* deg    = (int*)ws;
        float* agg1 = ws + n;
        float* agg2 = ws + 2 * n;
        float* dinv = ws + 4 * n;
        float* s    = ws + 5 * n;
        float* z    = ws + 6 * n;
        (void)hipMemsetAsync(d_ws, 0, (size_t)(4 * n) * sizeof(float), stream);
        const int gridE = (N_EDGES + BS - 1) / BS;
        const int gridN = (n + BS - 1) / BS;
        f_deg<<<gridE, BS, 0, stream>>>(dst, deg);
        f_node1<<<gridN, BS, 0, stream>>>(x, deg, dinv, s);
        f_scatter1<<<gridE, BS, 0, stream>>>(src, dst, s, agg1);
        f_node2<<<gridN, BS, 0, stream>>>(dinv, s, agg1, W1, b1, W2, (float2*)z);
        f_scatter2<<<gridE, BS, 0, stream>>>(src, dst, (const float2*)z, agg2);
        f_out<<<gridN, BS, 0, stream>>>(dinv, (const float2*)z, (const float2*)agg2,
                                        b2, (float2*)out);
    }
}

// Round 6
// 107.915 us; speedup vs baseline: 1.3598x; 1.3598x over previous
//
#include <hip/hip_runtime.h>

#define N_NODES 100000
#define N_EDGES 3200000
#define NB 782              // buckets of 128 nodes: ceil(100000/128)
#define NBP 1024            // bins padded for scan
#define NHB 256             // binning blocks (== BS so consumers get 1 run/thread)
#define EPB (N_EDGES / NHB) // 12500 edges per binning block (exact)
#define BSB 512             // binning block threads
#define BS 256              // consumer block threads

// ---------- fused binning: per-block LDS counting sort, linear flush ----------
// binned layout is BLOCK-major: block blk owns binned[blk*EPB .. blk*EPB+EPB).
// Within a region, edges are grouped by bucket; runinfo[blk*NB+b] = off|(cnt<<16)
// gives bucket b's run inside region blk. packed edge = (src<<7)|(dst&127).
__global__ __launch_bounds__(BSB) void k_bin2(const int* __restrict__ src,
                                              const int* __restrict__ dst,
                                              unsigned* __restrict__ binned,
                                              unsigned* __restrict__ runinfo) {
    __shared__ int hist[NBP];
    __shared__ int scanv[NBP];
    __shared__ int sh[BSB];
    __shared__ alignas(16) unsigned stage[EPB];
    int t = threadIdx.x, blk = blockIdx.x;
    for (int b = t; b < NBP; b += BSB) hist[b] = 0;
    __syncthreads();
    int base = blk * EPB;
    for (int i = t * 4; i < EPB; i += BSB * 4) {
        int4 d = *(const int4*)(dst + base + i);
        atomicAdd(&hist[d.x >> 7], 1);
        atomicAdd(&hist[d.y >> 7], 1);
        atomicAdd(&hist[d.z >> 7], 1);
        atomicAdd(&hist[d.w >> 7], 1);
    }
    __syncthreads();
    // exclusive scan over NBP padded bins; thread t owns bins 2t, 2t+1
    int b0 = hist[2 * t], b1 = hist[2 * t + 1];
    int v = b0 + b1;
    sh[t] = v;
    __syncthreads();
    for (int off = 1; off < BSB; off <<= 1) {
        int u = (t >= off) ? sh[t - off] : 0;
        __syncthreads();
        sh[t] += u;
        __syncthreads();
    }
    int excl = sh[t] - v;
    scanv[2 * t] = excl;
    scanv[2 * t + 1] = excl + b0;
    __syncthreads();
    // publish run info (reads scanv/hist) before cursors get bumped
    for (int b = t; b < NB; b += BSB)
        runinfo[(size_t)blk * NB + b] =
            (unsigned)scanv[b] | ((unsigned)hist[b] << 16);
    __syncthreads();
    // scatter into LDS stage using scanv as cursors
    for (int i = t * 4; i < EPB; i += BSB * 4) {
        int4 s4 = *(const int4*)(src + base + i);
        int4 d4 = *(const int4*)(dst + base + i);
        int p;
        p = atomicAdd(&scanv[d4.x >> 7], 1);
        stage[p] = ((unsigned)s4.x << 7) | (unsigned)(d4.x & 127);
        p = atomicAdd(&scanv[d4.y >> 7], 1);
        stage[p] = ((unsigned)s4.y << 7) | (unsigned)(d4.y & 127);
        p = atomicAdd(&scanv[d4.z >> 7], 1);
        stage[p] = ((unsigned)s4.z << 7) | (unsigned)(d4.z & 127);
        p = atomicAdd(&scanv[d4.w >> 7], 1);
        stage[p] = ((unsigned)s4.w << 7) | (unsigned)(d4.w & 127);
    }
    __syncthreads();
    // linear coalesced flush of the whole region
    for (int i = t * 4; i < EPB; i += BSB * 4)
        *(int4*)(binned + (size_t)blk * EPB + i) = *(const int4*)(stage + i);
}

// ---------- consumer 1: degree + node1 (dinv, s) ----------
__global__ __launch_bounds__(BS) void k_deg_node1(
        const unsigned* __restrict__ binned, const unsigned* __restrict__ runinfo,
        const float* __restrict__ x, float* __restrict__ dinv,
        float* __restrict__ s) {
    __shared__ int cnt[4][136];
    int t = threadIdx.x, b = blockIdx.x;
    for (int i = t; i < 4 * 136; i += BS) ((int*)cnt)[i] = 0;
    __syncthreads();
    unsigned ri = runinfo[(size_t)t * NB + b];  // run of bucket b in region t
    int off = (int)(ri & 0xFFFFu), c = (int)(ri >> 16);
    const unsigned* p = binned + (size_t)t * EPB + off;
    int rep = t & 3;
    for (int j = 0; j < c; ++j) {
        unsigned rd = p[j];
        atomicAdd(&cnt[rep][rd & 127], 1);
    }
    __syncthreads();
    int node = b * 128 + t;
    if (t < 128 && node < N_NODES) {
        int d = cnt[0][t] + cnt[1][t] + cnt[2][t] + cnt[3][t];
        float di = rsqrtf((float)(d + 1));  // +1 self-loop
        dinv[node] = di;
        s[node] = di * x[node];
    }
}

// ---------- consumer 2: scatter1 + layer-1 MLP -> z ----------
__global__ __launch_bounds__(BS) void k_s1n2(
        const unsigned* __restrict__ binned, const unsigned* __restrict__ runinfo,
        const float* __restrict__ dinv, const float* __restrict__ s,
        const float* __restrict__ W1, const float* __restrict__ b1,
        const float* __restrict__ W2, float2* __restrict__ z) {
    __shared__ float acc[4][136];
    int t = threadIdx.x, b = blockIdx.x;
    for (int i = t; i < 4 * 136; i += BS) ((float*)acc)[i] = 0.f;
    __syncthreads();
    unsigned ri = runinfo[(size_t)t * NB + b];
    int off = (int)(ri & 0xFFFFu), c = (int)(ri >> 16);
    const unsigned* p = binned + (size_t)t * EPB + off;
    int rep = t & 3;
    for (int j = 0; j < c; ++j) {
        unsigned rd = p[j];
        atomicAdd(&acc[rep][rd & 127], s[rd >> 7]);
    }
    __syncthreads();
    int node = b * 128 + t;
    if (t < 128 && node < N_NODES) {
        float aggv = acc[0][t] + acc[1][t] + acc[2][t] + acc[3][t];
        float di = dinv[node];
        float a = di * (aggv + s[node]);  // s[node] = self-loop term
        float z0 = 0.f, z1 = 0.f;
#pragma unroll
        for (int f = 0; f < 16; ++f) {
            float h = fmaxf(a * W1[f] + b1[f], 0.f);
            z0 += h * W2[2 * f + 0];
            z1 += h * W2[2 * f + 1];
        }
        z[node] = make_float2(di * z0, di * z1);
    }
}

// ---------- consumer 3: scatter2 + epilogue -> out ----------
__global__ __launch_bounds__(BS) void k_s2out(
        const unsigned* __restrict__ binned, const unsigned* __restrict__ runinfo,
        const float* __restrict__ dinv, const float2* __restrict__ z,
        const float* __restrict__ b2, float2* __restrict__ out) {
    __shared__ float accx[4][136], accy[4][136];
    int t = threadIdx.x, b = blockIdx.x;
    for (int i = t; i < 4 * 136; i += BS) {
        ((float*)accx)[i] = 0.f;
        ((float*)accy)[i] = 0.f;
    }
    __syncthreads();
    unsigned ri = runinfo[(size_t)t * NB + b];
    int off = (int)(ri & 0xFFFFu), c = (int)(ri >> 16);
    const unsigned* p = binned + (size_t)t * EPB + off;
    int rep = t & 3;
    for (int j = 0; j < c; ++j) {
        unsigned rd = p[j];
        float2 zz = z[rd >> 7];
        atomicAdd(&accx[rep][rd & 127], zz.x);
        atomicAdd(&accy[rep][rd & 127], zz.y);
    }
    __syncthreads();
    int node = b * 128 + t;
    if (t < 128 && node < N_NODES) {
        float ax = accx[0][t] + accx[1][t] + accx[2][t] + accx[3][t];
        float ay = accy[0][t] + accy[1][t] + accy[2][t] + accy[3][t];
        float di = dinv[node];
        float2 zz = z[node];
        out[node] = make_float2(di * (ax + zz.x) + b2[0],
                                di * (ay + zz.y) + b2[1]);
    }
}

// ---------- fallback (device atomics), used only if ws too small ----------
__global__ void f_deg(const int* __restrict__ dst, int* __restrict__ deg) {
    int i = blockIdx.x * blockDim.x + threadIdx.x;
    if (i < N_EDGES) atomicAdd(&deg[dst[i]], 1);
}
__global__ void f_node1(const float* __restrict__ x, const int* __restrict__ deg,
                        float* __restrict__ dinv, float* __restrict__ s) {
    int v = blockIdx.x * blockDim.x + threadIdx.x;
    if (v < N_NODES) {
        float di = rsqrtf((float)(deg[v] + 1));
        dinv[v] = di;
        s[v] = di * x[v];
    }
}
__global__ void f_scatter1(const int* __restrict__ src, const int* __restrict__ dst,
                           const float* __restrict__ s, float* __restrict__ agg1) {
    int i = blockIdx.x * blockDim.x + threadIdx.x;
    if (i < N_EDGES) atomicAdd(&agg1[dst[i]], s[src[i]]);
}
__global__ void f_node2(const float* __restrict__ dinv, const float* __restrict__ s,
                        const float* __restrict__ agg1, const float* __restrict__ W1,
                        const float* __restrict__ b1, const float* __restrict__ W2,
                        float2* __restrict__ z) {
    int v = blockIdx.x * blockDim.x + threadIdx.x;
    if (v < N_NODES) {
        float di = dinv[v];
        float a = di * (agg1[v] + s[v]);
        float z0 = 0.f, z1 = 0.f;
#pragma unroll
        for (int f = 0; f < 16; ++f) {
            float h = fmaxf(a * W1[f] + b1[f], 0.f);
            z0 += h * W2[2 * f + 0];
            z1 += h * W2[2 * f + 1];
        }
        z[v] = make_float2(di * z0, di * z1);
    }
}
__global__ void f_scatter2(const int* __restrict__ src, const int* __restrict__ dst,
                           const float2* __restrict__ z, float* __restrict__ agg2) {
    int i = blockIdx.x * blockDim.x + threadIdx.x;
    if (i < N_EDGES) {
        float2 zz = z[src[i]];
        int d = dst[i];
        atomicAdd(&agg2[2 * d + 0], zz.x);
        atomicAdd(&agg2[2 * d + 1], zz.y);
    }
}
__global__ void f_out(const float* __restrict__ dinv, const float2* __restrict__ z,
                      const float2* __restrict__ agg2, const float* __restrict__ b2,
                      float2* __restrict__ out) {
    int v = blockIdx.x * blockDim.x + threadIdx.x;
    if (v < N_NODES) {
        float di = dinv[v];
        float2 a = agg2[v], zz = z[v];
        out[v] = make_float2(di * (a.x + zz.x) + b2[0], di * (a.y + zz.y) + b2[1]);
    }
}

// ---------- launch ----------
extern "C" void kernel_launch(void* const* d_in, const int* in_sizes, int n_in,
                              void* d_out, int out_size, void* d_ws, size_t ws_size,
                              hipStream_t stream) {
    const float* x  = (const float*)d_in[0];
    const int* eidx = (const int*)d_in[1];
    const float* W1 = (const float*)d_in[2];
    const float* b1 = (const float*)d_in[3];
    const float* W2 = (const float*)d_in[4];
    const float* b2 = (const float*)d_in[5];
    float* out = (float*)d_out;

    const int n = N_NODES;
    const int* src = eidx;
    const int* dst = eidx + N_EDGES;

    // workspace layout (32-bit words):
    // runinfo[NHB*NB] | binned[E] | dinv[n] | s[n] | z[2n]
    size_t oRun  = 0;
    size_t oBin  = oRun + (size_t)NHB * NB;
    size_t oDinv = oBin + N_EDGES;
    size_t oS    = oDinv + n;
    size_t oZ    = oS + n;
    size_t need  = (oZ + 2 * n) * sizeof(int);

    if (ws_size >= need) {
        int* wsI = (int*)d_ws;
        unsigned* runinfo = (unsigned*)(wsI + oRun);
        unsigned* binned  = (unsigned*)(wsI + oBin);
        float* dinv = (float*)(wsI + oDinv);
        float* s    = (float*)(wsI + oS);
        float* z    = (float*)(wsI + oZ);

        k_bin2<<<NHB, BSB, 0, stream>>>(src, dst, binned, runinfo);
        k_deg_node1<<<NB, BS, 0, stream>>>(binned, runinfo, x, dinv, s);
        k_s1n2<<<NB, BS, 0, stream>>>(binned, runinfo, dinv, s, W1, b1, W2,
                                      (float2*)z);
        k_s2out<<<NB, BS, 0, stream>>>(binned, runinfo, dinv, (const float2*)z,
                                       b2, (float2*)out);
    } else {
        float* ws = (float*)d_ws;
        int* deg    = (int*)ws;
        float* agg1 = ws + n;
        float* agg2 = ws + 2 * n;
        float* dinv = ws + 4 * n;
        float* s    = ws + 5 * n;
        float* z    = ws + 6 * n;
        (void)hipMemsetAsync(d_ws, 0, (size_t)(4 * n) * sizeof(float), stream);
        const int gridE = (N_EDGES + BS - 1) / BS;
        const int gridN = (n + BS - 1) / BS;
        f_deg<<<gridE, BS, 0, stream>>>(dst, deg);
        f_node1<<<gridN, BS, 0, stream>>>(x, deg, dinv, s);
        f_scatter1<<<gridE, BS, 0, stream>>>(src, dst, s, agg1);
        f_node2<<<gridN, BS, 0, stream>>>(dinv, s, agg1, W1, b1, W2, (float2*)z);
        f_scatter2<<<gridE, BS, 0, stream>>>(src, dst, (const float2*)z, agg2);
        f_out<<<gridN, BS, 0, stream>>>(dinv, (const float2*)z, (const float2*)agg2,
                                        b2, (float2*)out);
    }
}